// Round 2
// baseline (745.860 us; speedup 1.0000x reference)
//
#include <hip/hip_runtime.h>

typedef __bf16 bf16_t;
typedef bf16_t bf16x8 __attribute__((ext_vector_type(8)));
typedef float f32x4 __attribute__((ext_vector_type(4)));
typedef unsigned short u16;

#define T_DIM 2048
#define N_DIM 1024
#define D_DIM 128
#define BH_DIM 16

__device__ __forceinline__ u16 f32_to_bf16(float f) {
    unsigned int u = __builtin_bit_cast(unsigned int, f);
    u += 0x7FFFu + ((u >> 16) & 1u);   // round-to-nearest-even
    return (u16)(u >> 16);
}

// ---- Kernel 1: RoPE + bf16 cast. 4 pairs/thread, HW sin/cos (revolutions). ----
__global__ void rope_kernel(const float* __restrict__ Q, u16* __restrict__ QR) {
    const int g = blockIdx.x * 256 + threadIdx.x;     // group of 4 pairs (32B in, 16B out)
    const int base = g * 4;                           // pair index
    const int t  = (base >> 9) & (T_DIM - 1);         // 512 pairs per row; groups never cross rows
    const int p0 = base & 511;
    const float4 qa = ((const float4*)Q)[g * 2];
    const float4 qb = ((const float4*)Q)[g * 2 + 1];
    const float vin[4][2] = {{qa.x, qa.y}, {qa.z, qa.w}, {qb.x, qb.y}, {qb.z, qb.w}};
    u16 ov[8];
    #pragma unroll
    for (int uu = 0; uu < 4; ++uu) {
        // freq = 2^(-p/32) / (2pi); phase kept in revolutions -> v_sin/v_cos direct
        const float freq = exp2f((float)(p0 + uu) * (-1.0f / 32.0f)) * 0.15915494309189535f;
        float ph = (float)t * freq;
        ph = ph - floorf(ph);
        const float s = __builtin_amdgcn_sinf(ph);
        const float c = __builtin_amdgcn_cosf(ph);
        ov[2 * uu]     = f32_to_bf16(vin[uu][0] * c - vin[uu][1] * s);
        ov[2 * uu + 1] = f32_to_bf16(vin[uu][1] * c + vin[uu][0] * s);
    }
    ((uint4*)QR)[g] = *(const uint4*)ov;
}

// ---- Kernel 2: V -> bf16, transposed to Vt[bh][d][t] via LDS tile ----
__global__ void vt_kernel(const float* __restrict__ V, u16* __restrict__ Vt) {
    __shared__ u16 tile[64][65];
    const int bh   = blockIdx.x >> 6;
    const int rem  = blockIdx.x & 63;
    const int tblk = rem >> 1;
    const int dblk = rem & 1;
    const int t0 = tblk * 64, d0 = dblk * 64;
    const float* src = V + ((size_t)bh * T_DIM + t0) * D_DIM + d0;
    #pragma unroll
    for (int k = 0; k < 16; ++k) {
        int linear = k * 256 + threadIdx.x;
        int r = linear >> 6, c = linear & 63;
        tile[r][c] = f32_to_bf16(src[(size_t)r * D_DIM + c]);
    }
    __syncthreads();
    u16* dst = Vt + ((size_t)bh * D_DIM + d0) * T_DIM + t0;
    #pragma unroll
    for (int k = 0; k < 16; ++k) {
        int linear = k * 256 + threadIdx.x;
        int dr = linear >> 6, tc = linear & 63;
        dst[(size_t)dr * T_DIM + tc] = tile[tc][dr];
    }
}

// ---- Kernel 3: core. One block = (bh, q-tile of 128, chunk of <=2 key-tiles). ----
// S fragments loaded DIRECTLY from global (row-major K-contiguous == MFMA frag
// layout) -> no LDS staging, no barriers anywhere. LDS only for the wave-private
// P layout transform. Output accumulated via atomicAdd into zeroed Out.
__global__ __launch_bounds__(256, 2)
void attn_kernel(const u16* __restrict__ QR, const u16* __restrict__ Vt,
                 float* __restrict__ Out) {
    __shared__ __align__(16) u16 Ps[128][136];

    // decode blockIdx -> (bh, qt, chunk); uniform ~2 j-tiles of work per block
    const int bh = blockIdx.x & 15;
    const int u  = blockIdx.x >> 4;          // 0..71
    int qt = 15, cum = 0;
    for (int q = 0; q < 16; ++q) {
        const int nc = (q + 2) >> 1;         // ceil((q+1)/2) chunks for q-tile q
        if (u < cum + nc) { qt = q; break; }
        cum += nc;
    }
    const int chunk = u - cum;
    const int jbeg = chunk * 2;
    const int jend = min(jbeg + 2, qt + 1);

    const int tid  = threadIdx.x;
    const int w    = tid >> 6;
    const int lane = tid & 63;
    const int quad = lane >> 4;
    const int l15  = lane & 15;

    const u16* QRb   = QR + (size_t)bh * (T_DIM * N_DIM);
    const u16* Ap    = QRb + (size_t)(qt * 128 + w * 32 + l15) * N_DIM + quad * 8;
    const u16* Vbase = Vt + (size_t)bh * (D_DIM * T_DIM) + (size_t)l15 * T_DIM + quad * 8;

    const f32x4 fz = {0.f, 0.f, 0.f, 0.f};
    f32x4 o_acc[2][8];
    #pragma unroll
    for (int mi = 0; mi < 2; ++mi)
        #pragma unroll
        for (int nj = 0; nj < 8; ++nj)
            o_acc[mi][nj] = fz;

    for (int j = jbeg; j < jend; ++j) {
        const u16* Bp = QRb + (size_t)(j * 128 + l15) * N_DIM + quad * 8;
        f32x4 s_acc[2][8];
        #pragma unroll
        for (int mi = 0; mi < 2; ++mi)
            #pragma unroll
            for (int nj = 0; nj < 8; ++nj)
                s_acc[mi][nj] = fz;

        #pragma unroll 2
        for (int k0 = 0; k0 < N_DIM; k0 += 32) {
            const bf16x8 a0 = *(const bf16x8*)(Ap + k0);
            const bf16x8 a1 = *(const bf16x8*)(Ap + 16 * N_DIM + k0);
            #pragma unroll
            for (int nj = 0; nj < 8; ++nj) {
                const bf16x8 bv = *(const bf16x8*)(Bp + (size_t)(nj * 16) * N_DIM + k0);
                s_acc[0][nj] = __builtin_amdgcn_mfma_f32_16x16x32_bf16(a0, bv, s_acc[0][nj], 0, 0, 0);
                s_acc[1][nj] = __builtin_amdgcn_mfma_f32_16x16x32_bf16(a1, bv, s_acc[1][nj], 0, 0, 0);
            }
        }

        if (j == qt) {   // strict causal on the diagonal tile: keep col < row
            #pragma unroll
            for (int mi = 0; mi < 2; ++mi) {
                const int rowb = w * 32 + mi * 16 + quad * 4;
                #pragma unroll
                for (int nj = 0; nj < 8; ++nj) {
                    const int col = nj * 16 + l15;
                    #pragma unroll
                    for (int r = 0; r < 4; ++r)
                        if (col >= rowb + r) s_acc[mi][nj][r] = 0.f;
                }
            }
        }

        // C/D layout -> A-operand layout via LDS; wave-private rows, no barrier.
        #pragma unroll
        for (int mi = 0; mi < 2; ++mi) {
            const int rowb = w * 32 + mi * 16 + quad * 4;
            #pragma unroll
            for (int nj = 0; nj < 8; ++nj) {
                const int col = nj * 16 + l15;
                #pragma unroll
                for (int r = 0; r < 4; ++r)
                    Ps[rowb + r][col] = f32_to_bf16(s_acc[mi][nj][r]);
            }
        }

        #pragma unroll
        for (int kc = 0; kc < 4; ++kc) {
            const int k0 = kc * 32 + quad * 8;
            const bf16x8 p0 = *(const bf16x8*)(&Ps[w * 32 + l15][k0]);
            const bf16x8 p1 = *(const bf16x8*)(&Ps[w * 32 + 16 + l15][k0]);
            #pragma unroll
            for (int nj = 0; nj < 8; ++nj) {
                const bf16x8 vv = *(const bf16x8*)(Vbase + (size_t)(nj * 16) * T_DIM + j * 128 + kc * 32);
                o_acc[0][nj] = __builtin_amdgcn_mfma_f32_16x16x32_bf16(p0, vv, o_acc[0][nj], 0, 0, 0);
                o_acc[1][nj] = __builtin_amdgcn_mfma_f32_16x16x32_bf16(p1, vv, o_acc[1][nj], 0, 0, 0);
            }
        }
    }

    float* obase = Out + ((size_t)bh * T_DIM + (size_t)qt * 128) * D_DIM;
    #pragma unroll
    for (int mi = 0; mi < 2; ++mi)
        #pragma unroll
        for (int nj = 0; nj < 8; ++nj)
            #pragma unroll
            for (int r = 0; r < 4; ++r)
                atomicAdd(&obase[(size_t)(w * 32 + mi * 16 + quad * 4 + r) * D_DIM + nj * 16 + l15],
                          o_acc[mi][nj][r]);
}

extern "C" void kernel_launch(void* const* d_in, const int* in_sizes, int n_in,
                              void* d_out, int out_size, void* d_ws, size_t ws_size,
                              hipStream_t stream) {
    const float* Q = (const float*)d_in[0];
    // d_in[1] is K == Q (reference asserts identity) — unused
    const float* V = (const float*)d_in[2];

    // ws layout: QR bf16 (67.1 MB) | Vt bf16 (8.4 MB)
    u16* QRw = (u16*)d_ws;
    u16* Vtw = QRw + (size_t)BH_DIM * T_DIM * N_DIM;
    float* Out = (float*)d_out;

    hipMemsetAsync(d_out, 0, (size_t)out_size * sizeof(float), stream);
    rope_kernel<<<dim3(16384), dim3(256), 0, stream>>>(Q, QRw);
    vt_kernel<<<dim3(1024), dim3(256), 0, stream>>>(V, Vtw);
    attn_kernel<<<dim3(1152), dim3(256), 0, stream>>>(QRw, Vtw, Out);
}

// Round 3
// 527.106 us; speedup vs baseline: 1.4150x; 1.4150x over previous
//
#include <hip/hip_runtime.h>

typedef __bf16 bf16_t;
typedef bf16_t bf16x8 __attribute__((ext_vector_type(8)));
typedef float f32x4 __attribute__((ext_vector_type(4)));
typedef unsigned short u16;
typedef unsigned int u32;

#define T_DIM 2048
#define N_DIM 1024
#define D_DIM 128

__device__ __forceinline__ u16 f32_to_bf16(float f) {
    u32 u = __builtin_bit_cast(u32, f);
    u += 0x7FFFu + ((u >> 16) & 1u);   // RNE
    return (u16)(u >> 16);
}
__device__ __forceinline__ float bf16_to_f32(u16 v) {
    u32 u = (u32)v << 16;
    return __builtin_bit_cast(float, u);
}

typedef __attribute__((address_space(1))) const u32 guint;
typedef __attribute__((address_space(3))) u32 luint;
// async global->LDS, 16B per lane, LDS dst = wave-uniform base + lane*16
__device__ __forceinline__ void stage16(const void* g, void* l) {
    __builtin_amdgcn_global_load_lds((guint*)g, (luint*)l, 16, 0, 0);
}

// ---- Kernel 1: RoPE + bf16 cast. 4 pairs/thread, HW sin/cos (revolutions). ----
__global__ void rope_kernel(const float* __restrict__ Q, u16* __restrict__ QR) {
    const int g = blockIdx.x * 256 + threadIdx.x;
    const int base = g * 4;
    const int t  = (base >> 9) & (T_DIM - 1);
    const int p0 = base & 511;
    const float4 qa = ((const float4*)Q)[g * 2];
    const float4 qb = ((const float4*)Q)[g * 2 + 1];
    const float vin[4][2] = {{qa.x, qa.y}, {qa.z, qa.w}, {qb.x, qb.y}, {qb.z, qb.w}};
    u16 ov[8];
    #pragma unroll
    for (int uu = 0; uu < 4; ++uu) {
        const float freq = exp2f((float)(p0 + uu) * (-1.0f / 32.0f)) * 0.15915494309189535f;
        float ph = (float)t * freq;
        ph = ph - floorf(ph);
        const float s = __builtin_amdgcn_sinf(ph);
        const float c = __builtin_amdgcn_cosf(ph);
        ov[2 * uu]     = f32_to_bf16(vin[uu][0] * c - vin[uu][1] * s);
        ov[2 * uu + 1] = f32_to_bf16(vin[uu][1] * c + vin[uu][0] * s);
    }
    ((uint4*)QR)[g] = *(const uint4*)ov;
}

// ---- Kernel 2: V -> bf16, transposed to Vt[bh][d][t] ----
__global__ void vt_kernel(const float* __restrict__ V, u16* __restrict__ Vt) {
    __shared__ u16 tile[64][65];
    const int bh   = blockIdx.x >> 6;
    const int rem  = blockIdx.x & 63;
    const int t0 = (rem >> 1) * 64, d0 = (rem & 1) * 64;
    const float* src = V + ((size_t)bh * T_DIM + t0) * D_DIM + d0;
    #pragma unroll
    for (int k = 0; k < 16; ++k) {
        int linear = k * 256 + threadIdx.x;
        int r = linear >> 6, c = linear & 63;
        tile[r][c] = f32_to_bf16(src[(size_t)r * D_DIM + c]);
    }
    __syncthreads();
    u16* dst = Vt + ((size_t)bh * D_DIM + d0) * T_DIM + t0;
    #pragma unroll
    for (int k = 0; k < 16; ++k) {
        int linear = k * 256 + threadIdx.x;
        int dr = linear >> 6, tc = linear & 63;
        dst[(size_t)dr * T_DIM + tc] = tile[tc][dr];
    }
}

// run b covers items [start, start+len): blocks 0..127 get 5 items, 128..511 get 4.
__device__ __forceinline__ int run_start(int b) { return b < 128 ? 5 * b : 640 + 4 * (b - 128); }

// ---- Kernel 3: persistent-run attention core (m97-style staging). ----
__global__ __launch_bounds__(256, 2)
void attn_kernel(const u16* __restrict__ QR, const u16* __restrict__ Vt,
                 float* __restrict__ Out, u16* __restrict__ Part) {
    // As/Bs: 128x64 bf16 each (32768 B, global_load_lds layout, XOR-swizzled cols)
    // Ps: 128x140 bf16 (35840 B) aliased on top.
    __shared__ __align__(16) u16 Smem[17920];
    u16 (*As)[64]  = (u16 (*)[64])Smem;
    u16 (*Bs)[64]  = (u16 (*)[64])(Smem + 8192);
    u16 (*Ps)[140] = (u16 (*)[140])Smem;

    const int b     = blockIdx.x;
    const int start = run_start(b);
    const int len   = b < 128 ? 5 : 4;

    const int tid  = threadIdx.x;
    const int w    = tid >> 6;
    const int wy   = w >> 1, wx = w & 1;
    const int lane = tid & 63;
    const int quad = lane >> 4;
    const int l15  = lane & 15;
    const int sw   = l15 & 7;                       // XOR swizzle key for frag reads
    const int srow = lane >> 3;                      // staging: sub-row 0..7
    const int scol = (lane & 7) ^ (srow & 7);        // staging: swizzled 16B-chunk

    const f32x4 fz = {0.f, 0.f, 0.f, 0.f};
    f32x4 o_acc[4][4];
    int cur_bh = -1, cur_qt = -1;
    bool hasj0 = false;
    const u16* QRb = QR;
    const u16* Ap  = QR;   // staging base for A rows (set on tile change)
    const u16* Vb  = Vt;

    for (int it = 0; it < len; ++it) {
        const int i = start + it;
        const int bh = i / 136;
        const int r  = i - bh * 136;
        int qt = 15, j = 0, acc = 0;
        #pragma unroll 1
        for (int q = 0; q < 16; ++q) {
            if (r < acc + q + 1) { qt = q; j = r - acc; break; }
            acc += q + 1;
        }

        if (qt != cur_qt || bh != cur_bh) {
            if (cur_qt >= 0) {   // flush previous tile
                if (hasj0) {
                    float* ob = Out + ((size_t)cur_bh * T_DIM + (size_t)cur_qt * 128) * D_DIM;
                    #pragma unroll
                    for (int mi = 0; mi < 4; ++mi)
                        #pragma unroll
                        for (int nj = 0; nj < 4; ++nj)
                            #pragma unroll
                            for (int rr = 0; rr < 4; ++rr)
                                ob[(size_t)(wy * 64 + mi * 16 + quad * 4 + rr) * D_DIM + wx * 64 + nj * 16 + l15] = o_acc[mi][nj][rr];
                } else {
                    u16* pb = Part + (size_t)b * 16384;
                    #pragma unroll
                    for (int mi = 0; mi < 4; ++mi)
                        #pragma unroll
                        for (int nj = 0; nj < 4; ++nj)
                            #pragma unroll
                            for (int rr = 0; rr < 4; ++rr)
                                pb[(wy * 64 + mi * 16 + quad * 4 + rr) * 128 + wx * 64 + nj * 16 + l15] = f32_to_bf16(o_acc[mi][nj][rr]);
                }
            }
            cur_bh = bh; cur_qt = qt; hasj0 = (j == 0);
            #pragma unroll
            for (int mi = 0; mi < 4; ++mi)
                #pragma unroll
                for (int nj = 0; nj < 4; ++nj)
                    o_acc[mi][nj] = fz;
            QRb = QR + (size_t)bh * (T_DIM * N_DIM);
            Ap  = QRb + (size_t)(qt * 128 + w * 32 + srow) * N_DIM + scol * 8;
            Vb  = Vt + (size_t)bh * (D_DIM * T_DIM) + (size_t)(wx * 64 + l15) * T_DIM + quad * 8;
        }

        const u16* Bp = QRb + (size_t)(j * 128 + w * 32 + srow) * N_DIM + scol * 8;
        f32x4 s_acc[4][4];
        #pragma unroll
        for (int mi = 0; mi < 4; ++mi)
            #pragma unroll
            for (int nj = 0; nj < 4; ++nj)
                s_acc[mi][nj] = fz;

        __syncthreads();   // prior item's Ps reads done before staging overwrites

        for (int kk = 0; kk < N_DIM; kk += 64) {
            #pragma unroll
            for (int ii = 0; ii < 4; ++ii) {
                stage16(Ap + (size_t)ii * 8 * N_DIM + kk, &As[w * 32 + ii * 8][0]);
                stage16(Bp + (size_t)ii * 8 * N_DIM + kk, &Bs[w * 32 + ii * 8][0]);
            }
            __syncthreads();
            #pragma unroll
            for (int kc = 0; kc < 2; ++kc) {
                bf16x8 af[4], bfr[4];
                #pragma unroll
                for (int mi = 0; mi < 4; ++mi)
                    af[mi] = *(const bf16x8*)((const char*)As + (wy * 64 + mi * 16 + l15) * 128 + (((kc * 4 + quad) ^ sw) << 4));
                #pragma unroll
                for (int nj = 0; nj < 4; ++nj)
                    bfr[nj] = *(const bf16x8*)((const char*)Bs + (wx * 64 + nj * 16 + l15) * 128 + (((kc * 4 + quad) ^ sw) << 4));
                #pragma unroll
                for (int mi = 0; mi < 4; ++mi)
                    #pragma unroll
                    for (int nj = 0; nj < 4; ++nj)
                        s_acc[mi][nj] = __builtin_amdgcn_mfma_f32_16x16x32_bf16(af[mi], bfr[nj], s_acc[mi][nj], 0, 0, 0);
            }
            __syncthreads();
        }

        if (j == qt) {   // strict causal on the diagonal tile: keep col < row
            #pragma unroll
            for (int mi = 0; mi < 4; ++mi) {
                const int rowb = wy * 64 + mi * 16 + quad * 4;
                #pragma unroll
                for (int nj = 0; nj < 4; ++nj) {
                    const int col = wx * 64 + nj * 16 + l15;
                    #pragma unroll
                    for (int rr = 0; rr < 4; ++rr)
                        if (col >= rowb + rr) s_acc[mi][nj][rr] = 0.f;
                }
            }
        }

        // C/D -> A-operand layout via LDS (cross-wave in wx => barrier both sides)
        #pragma unroll
        for (int mi = 0; mi < 4; ++mi) {
            const int rowb = wy * 64 + mi * 16 + quad * 4;
            #pragma unroll
            for (int nj = 0; nj < 4; ++nj) {
                const int col = wx * 64 + nj * 16 + l15;
                #pragma unroll
                for (int rr = 0; rr < 4; ++rr)
                    Ps[rowb + rr][col] = f32_to_bf16(s_acc[mi][nj][rr]);
            }
        }
        __syncthreads();

        const u16* vjb = Vb + j * 128;
        #pragma unroll
        for (int kc = 0; kc < 4; ++kc) {
            bf16x8 pf[4];
            #pragma unroll
            for (int mi = 0; mi < 4; ++mi)
                pf[mi] = *(const bf16x8*)(&Ps[wy * 64 + mi * 16 + l15][kc * 32 + quad * 8]);
            #pragma unroll
            for (int nj = 0; nj < 4; ++nj) {
                const bf16x8 vv = *(const bf16x8*)(vjb + (size_t)(nj * 16) * T_DIM + kc * 32);
                #pragma unroll
                for (int mi = 0; mi < 4; ++mi)
                    o_acc[mi][nj] = __builtin_amdgcn_mfma_f32_16x16x32_bf16(pf[mi], vv, o_acc[mi][nj], 0, 0, 0);
            }
        }
    }

    // flush last tile
    if (hasj0) {
        float* ob = Out + ((size_t)cur_bh * T_DIM + (size_t)cur_qt * 128) * D_DIM;
        #pragma unroll
        for (int mi = 0; mi < 4; ++mi)
            #pragma unroll
            for (int nj = 0; nj < 4; ++nj)
                #pragma unroll
                for (int rr = 0; rr < 4; ++rr)
                    ob[(size_t)(wy * 64 + mi * 16 + quad * 4 + rr) * D_DIM + wx * 64 + nj * 16 + l15] = o_acc[mi][nj][rr];
    } else {
        u16* pb = Part + (size_t)b * 16384;
        #pragma unroll
        for (int mi = 0; mi < 4; ++mi)
            #pragma unroll
            for (int nj = 0; nj < 4; ++nj)
                #pragma unroll
                for (int rr = 0; rr < 4; ++rr)
                    pb[(wy * 64 + mi * 16 + quad * 4 + rr) * 128 + wx * 64 + nj * 16 + l15] = f32_to_bf16(o_acc[mi][nj][rr]);
    }
}

// ---- Kernel 4: add partial tiles into Out. One block per (bh, qt>=1). ----
__global__ void combine_kernel(float* __restrict__ Out, const u16* __restrict__ Part) {
    const int bh = blockIdx.x & 15;
    const int qt = 1 + (blockIdx.x >> 4);
    const int ts = bh * 136 + (qt * (qt + 1)) / 2;   // item index of (bh,qt,j=0)
    const int lo = ts + 1, hi = ts + qt;
    int bmin = (lo <= 640) ? (lo + 4) / 5 : 128 + (lo - 640 + 3) / 4;
    int writers[4], nw = 0;
    for (int bb = bmin; bb < 512 && run_start(bb) <= hi && nw < 4; ++bb)
        writers[nw++] = bb;
    if (nw == 0) return;
    float* ob = Out + ((size_t)bh * T_DIM + (size_t)qt * 128) * D_DIM;
    const int tid = threadIdx.x;
    #pragma unroll 1
    for (int e = 0; e < 64; ++e) {
        const int idx = e * 256 + tid;
        float a = ob[idx];
        for (int k = 0; k < nw; ++k)
            a += bf16_to_f32(Part[(size_t)writers[k] * 16384 + idx]);
        ob[idx] = a;
    }
}

extern "C" void kernel_launch(void* const* d_in, const int* in_sizes, int n_in,
                              void* d_out, int out_size, void* d_ws, size_t ws_size,
                              hipStream_t stream) {
    const float* Q = (const float*)d_in[0];
    const float* V = (const float*)d_in[2];   // d_in[1] is K == Q, unused

    // ws: QR bf16 (67,108,864 B) | Vt bf16 (8,388,608 B) | Part bf16 (16,777,216 B)
    u16* QRw = (u16*)d_ws;
    u16* Vtw = QRw + (size_t)16 * T_DIM * N_DIM;
    u16* Part = Vtw + (size_t)16 * D_DIM * T_DIM;
    float* Out = (float*)d_out;

    rope_kernel<<<dim3(16384), dim3(256), 0, stream>>>(Q, QRw);
    vt_kernel<<<dim3(1024), dim3(256), 0, stream>>>(V, Vtw);
    attn_kernel<<<dim3(512), dim3(256), 0, stream>>>(QRw, Vtw, Out, Part);
    combine_kernel<<<dim3(240), dim3(256), 0, stream>>>(Out, Part);
}